// Round 1
// baseline (457.366 us; speedup 1.0000x reference)
//
#include <hip/hip_runtime.h>

typedef __attribute__((ext_vector_type(8))) short vbf8;   // 8 bf16 = 4 VGPR (MFMA A/B frag)
typedef __attribute__((ext_vector_type(4))) short vs4;    // 4 bf16 = 8 B
typedef __attribute__((ext_vector_type(4))) float vf4;    // MFMA C/D frag

#define NT 53
#define CD 256
#define NH 8

__device__ __forceinline__ short f2bf(float f) {
    union { float f; unsigned u; } v; v.f = f;
    return (short)((v.u + 0x7fffu + ((v.u >> 16) & 1u)) >> 16);  // RNE
}

// ---------------- Kernel 1: fused QKV + windowed attention ----------------
// One wave per window; 8 waves (=8 windows) per block.
// Layout logic (16x16x32 bf16 MFMA; C/D: col=lane&15, row=(lane>>4)*4+reg):
//   qT = Wq @ x^T  -> acc(col=token,row=hd) -> q_lds[token][hd]  (8B contiguous writes)
//   kT = Wk @ x^T  -> k_lds[token][hd]
//   v  = x @ Wv^T  -> acc(col=hd,row=token) -> vT_lds[hd][token]
//   S^T = k @ q^T  -> acc(col=query,row=key); softmax over keys = 16 local + 2 shfl_xor
//   pT_lds[query][key]; out^T = vT @ pT -> acc(col=query,row=hd); /l; bf16 global write
__launch_bounds__(512, 2)
__global__ void k1_fused(const float* __restrict__ x,
                         const float* __restrict__ qkv_w,
                         const float* __restrict__ qkv_b,
                         const float* __restrict__ tbl,
                         short* __restrict__ attn,
                         int win0)
{
    __shared__ short w_lds[32 * 256];     // current 32x256 weight slice, bf16, XOR-swizzled
    __shared__ float bias_lds[64 * 65];   // per-head bias [key][query], pads pre-masked
    __shared__ short wbuf[8][7424];       // per-wave scratch (14848 B)

    const int tid  = threadIdx.x;
    const int wave = tid >> 6;
    const int lane = tid & 63;
    const int c    = lane & 15;
    const int g    = lane >> 4;
    const int win  = win0 + (int)blockIdx.x * 8 + wave;

    short* qbuf  = wbuf[wave];            // [64][40] token x hd
    short* kbuf  = wbuf[wave] + 2560;     // [64][40]
    short* vtbuf = wbuf[wave] + 5120;     // [32][72] hd x token
    short* ptbuf = wbuf[wave];            // [64][72] query x key (aliases q+k)

    // ---- x fragments: xf[t16][ks]: lane holds x[t16*16+c][ks*32+g*8 .. +8] (bf16)
    // A-frag of x and B-frag of x^T are the same per-lane data -> reused for q,k,v, all heads.
    vbf8 xf[4][8];
    {
        const float* xb = x + (size_t)win * (NT * CD);
        #pragma unroll
        for (int mt = 0; mt < 4; ++mt) {
            const int row = mt * 16 + c;
            const float* src = xb + row * CD + g * 8;
            #pragma unroll
            for (int ks = 0; ks < 8; ++ks) {
                vbf8 r = {0, 0, 0, 0, 0, 0, 0, 0};
                if (row < NT) {
                    vf4 a = *(const vf4*)(src + ks * 32);
                    vf4 b = *(const vf4*)(src + ks * 32 + 4);
                    r[0] = f2bf(a[0]); r[1] = f2bf(a[1]); r[2] = f2bf(a[2]); r[3] = f2bf(a[3]);
                    r[4] = f2bf(b[0]); r[5] = f2bf(b[1]); r[6] = f2bf(b[2]); r[7] = f2bf(b[3]);
                }
                xf[mt][ks] = r;
            }
        }
    }

    auto stageW = [&](const float* wsrc) {
        #pragma unroll
        for (int it = 0; it < 2; ++it) {
            const int u   = tid + it * 512;     // 1024 x 16B units = 32 rows x 512 B
            const int row = u >> 5;
            const int seg = u & 31;
            const float* s = wsrc + row * 256 + seg * 8;
            vf4 a = *(const vf4*)s;
            vf4 b = *(const vf4*)(s + 4);
            vbf8 r;
            r[0] = f2bf(a[0]); r[1] = f2bf(a[1]); r[2] = f2bf(a[2]); r[3] = f2bf(a[3]);
            r[4] = f2bf(b[0]); r[5] = f2bf(b[1]); r[6] = f2bf(b[2]); r[7] = f2bf(b[3]);
            const int byte = row * 512 + ((seg * 16) ^ ((row & 7) << 4));
            *(vbf8*)((char*)w_lds + byte) = r;
        }
    };
    auto rdW = [&](int rr, int ks) -> vbf8 {
        const int byte = rr * 512 + (((ks * 64) + g * 16) ^ ((rr & 7) << 4));
        return *(const vbf8*)((const char*)w_lds + byte);
    };
    // qT/kT: acc (hd x token), +row bias, write dst[token][hd] (stride 40)
    auto qk_proj = [&](const float* bbase, short* dst) {
        vf4 a[2][4];
        #pragma unroll
        for (int mt = 0; mt < 2; ++mt)
            #pragma unroll
            for (int nt = 0; nt < 4; ++nt) { vf4 z = {0.f, 0.f, 0.f, 0.f}; a[mt][nt] = z; }
        #pragma unroll
        for (int mt = 0; mt < 2; ++mt) {
            #pragma unroll
            for (int ks = 0; ks < 8; ++ks) {
                vbf8 wf = rdW(mt * 16 + c, ks);
                #pragma unroll
                for (int nt = 0; nt < 4; ++nt)
                    a[mt][nt] = __builtin_amdgcn_mfma_f32_16x16x32_bf16(wf, xf[nt][ks], a[mt][nt], 0, 0, 0);
            }
        }
        #pragma unroll
        for (int mt = 0; mt < 2; ++mt) {
            vf4 qb = *(const vf4*)(bbase + mt * 16 + g * 4);
            #pragma unroll
            for (int nt = 0; nt < 4; ++nt) {
                vs4 o;
                #pragma unroll
                for (int r = 0; r < 4; ++r) o[r] = f2bf(a[mt][nt][r] + qb[r]);
                *(vs4*)(dst + (nt * 16 + c) * 40 + mt * 16 + g * 4) = o;
            }
        }
    };

    const float scale = 0.17677669529663687f;   // 32^-0.5

    #pragma unroll 1
    for (int h = 0; h < NH; ++h) {
        // ---------- Q weights + bias table ----------
        __syncthreads();
        stageW(qkv_w + (size_t)(h * 32) * 256);
        {
            #pragma unroll
            for (int it = 0; it < 8; ++it) {
                const int e = tid * 8 + it;      // 0..4095
                const int key = e >> 6, qq = e & 63;
                float bv;
                if (key >= NT) bv = -1e30f;                              // mask pad keys
                else if (key < 4 || qq < 4 || qq >= NT) bv = 0.f;        // carrier rows/cols
                else {
                    const int i = qq - 4, j = key - 4;                   // query, key in window
                    const int idx = ((i / 7) - (j / 7) + 6) * 13 + ((i % 7) - (j % 7) + 6);
                    bv = tbl[idx * NH + h];
                }
                bias_lds[key * 65 + qq] = bv;
            }
        }
        __syncthreads();
        qk_proj(qkv_b + h * 32, qbuf);
        // ---------- K ----------
        __syncthreads();
        stageW(qkv_w + (size_t)(256 + h * 32) * 256);
        __syncthreads();
        qk_proj(qkv_b + 256 + h * 32, kbuf);
        // ---------- V ----------
        __syncthreads();
        stageW(qkv_w + (size_t)(512 + h * 32) * 256);
        __syncthreads();
        {
            vf4 va[4][2];
            #pragma unroll
            for (int mt = 0; mt < 4; ++mt)
                #pragma unroll
                for (int nt = 0; nt < 2; ++nt) { vf4 z = {0.f, 0.f, 0.f, 0.f}; va[mt][nt] = z; }
            #pragma unroll
            for (int nt = 0; nt < 2; ++nt) {
                #pragma unroll
                for (int ks = 0; ks < 8; ++ks) {
                    vbf8 wf = rdW(nt * 16 + c, ks);
                    #pragma unroll
                    for (int mt = 0; mt < 4; ++mt)
                        va[mt][nt] = __builtin_amdgcn_mfma_f32_16x16x32_bf16(xf[mt][ks], wf, va[mt][nt], 0, 0, 0);
                }
            }
            #pragma unroll
            for (int nt = 0; nt < 2; ++nt) {
                const float vb = qkv_b[512 + h * 32 + nt * 16 + c];
                #pragma unroll
                for (int mt = 0; mt < 4; ++mt) {
                    vs4 o;
                    #pragma unroll
                    for (int r = 0; r < 4; ++r) o[r] = f2bf(va[mt][nt][r] + vb);
                    *(vs4*)(vtbuf + (nt * 16 + c) * 72 + mt * 16 + g * 4) = o;
                }
            }
        }
        // ---------- S^T = k @ q^T ----------
        vbf8 qf[4], kf[4];
        #pragma unroll
        for (int i = 0; i < 4; ++i) qf[i] = *(const vbf8*)(qbuf + (i * 16 + c) * 40 + g * 8);
        #pragma unroll
        for (int i = 0; i < 4; ++i) kf[i] = *(const vbf8*)(kbuf + (i * 16 + c) * 40 + g * 8);
        vf4 st[4][4];
        #pragma unroll
        for (int mk = 0; mk < 4; ++mk)
            #pragma unroll
            for (int nq = 0; nq < 4; ++nq) {
                vf4 z = {0.f, 0.f, 0.f, 0.f};
                st[mk][nq] = __builtin_amdgcn_mfma_f32_16x16x32_bf16(kf[mk], qf[nq], z, 0, 0, 0);
            }
        // ---------- bias + softmax over keys (per query column) ----------
        float linv[4];
        #pragma unroll
        for (int nq = 0; nq < 4; ++nq) {
            const int qq = nq * 16 + c;
            float mx = -1e30f;
            #pragma unroll
            for (int mk = 0; mk < 4; ++mk)
                #pragma unroll
                for (int r = 0; r < 4; ++r) {
                    const int key = mk * 16 + g * 4 + r;
                    float s = st[mk][nq][r] * scale + bias_lds[key * 65 + qq];
                    st[mk][nq][r] = s;
                    mx = fmaxf(mx, s);
                }
            mx = fmaxf(mx, __shfl_xor(mx, 16, 64));
            mx = fmaxf(mx, __shfl_xor(mx, 32, 64));
            float sum = 0.f;
            #pragma unroll
            for (int mk = 0; mk < 4; ++mk)
                #pragma unroll
                for (int r = 0; r < 4; ++r) {
                    float p = __expf(st[mk][nq][r] - mx);
                    st[mk][nq][r] = p;
                    sum += p;
                }
            sum += __shfl_xor(sum, 16, 64);
            sum += __shfl_xor(sum, 32, 64);
            linv[nq] = 1.f / sum;
        }
        // ---------- pT (unnormalized exp, bf16) ----------
        #pragma unroll
        for (int nq = 0; nq < 4; ++nq)
            #pragma unroll
            for (int mk = 0; mk < 4; ++mk) {
                vs4 o;
                #pragma unroll
                for (int r = 0; r < 4; ++r) o[r] = f2bf(st[mk][nq][r]);
                *(vs4*)(ptbuf + (nq * 16 + c) * 72 + mk * 16 + g * 4) = o;
            }
        // ---------- out^T = vT @ pT ----------
        vf4 ot[2][4];
        #pragma unroll
        for (int mt = 0; mt < 2; ++mt)
            #pragma unroll
            for (int nq = 0; nq < 4; ++nq) { vf4 z = {0.f, 0.f, 0.f, 0.f}; ot[mt][nq] = z; }
        #pragma unroll
        for (int ks = 0; ks < 2; ++ks) {
            vbf8 vfr[2], pfr[4];
            #pragma unroll
            for (int mt = 0; mt < 2; ++mt)
                vfr[mt] = *(const vbf8*)(vtbuf + (mt * 16 + c) * 72 + ks * 32 + g * 8);
            #pragma unroll
            for (int nq = 0; nq < 4; ++nq)
                pfr[nq] = *(const vbf8*)(ptbuf + (nq * 16 + c) * 72 + ks * 32 + g * 8);
            #pragma unroll
            for (int mt = 0; mt < 2; ++mt)
                #pragma unroll
                for (int nq = 0; nq < 4; ++nq)
                    ot[mt][nq] = __builtin_amdgcn_mfma_f32_16x16x32_bf16(vfr[mt], pfr[nq], ot[mt][nq], 0, 0, 0);
        }
        // ---------- normalize + write attn bf16, layout [win][token][C] ----------
        #pragma unroll
        for (int nq = 0; nq < 4; ++nq) {
            const int qq = nq * 16 + c;
            if (qq < NT) {
                #pragma unroll
                for (int mt = 0; mt < 2; ++mt) {
                    vs4 o;
                    #pragma unroll
                    for (int r = 0; r < 4; ++r) o[r] = f2bf(ot[mt][nq][r] * linv[nq]);
                    *(vs4*)(attn + ((size_t)(win - win0) * NT + qq) * CD + h * 32 + mt * 16 + g * 4) = o;
                }
            }
        }
    }
}

// ---------------- Kernel 2: output projection GEMM ----------------
// out[m][n] = sum_k attn[m][k] * proj_w[n][k] + proj_b[n];  BM=64, BN=256, BK=64, 4 waves.
__launch_bounds__(256, 4)
__global__ void k2_proj(const short* __restrict__ A,
                        const float* __restrict__ proj_w,
                        const float* __restrict__ proj_b,
                        float* __restrict__ out,
                        int Mc)
{
    __shared__ short a_lds[64 * 64];     // [row][k] bf16, swizzled (8 KB)
    __shared__ short b_lds[256 * 64];    // [n][k] bf16, swizzled (32 KB)

    const int tid  = threadIdx.x;
    const int wave = tid >> 6;
    const int lane = tid & 63;
    const int c    = lane & 15;
    const int g    = lane >> 4;
    const int m0   = (int)blockIdx.x * 64;

    vf4 acc[4][4];
    #pragma unroll
    for (int mt = 0; mt < 4; ++mt)
        #pragma unroll
        for (int nt = 0; nt < 4; ++nt) { vf4 z = {0.f, 0.f, 0.f, 0.f}; acc[mt][nt] = z; }

    for (int k0 = 0; k0 < 256; k0 += 64) {
        __syncthreads();
        // stage A tile
        #pragma unroll
        for (int rr = 0; rr < 2; ++rr) {
            const int u   = tid + rr * 256;      // 512 x 16B units
            const int row = u >> 3;
            const int seg = u & 7;
            int mrow = m0 + row; if (mrow >= Mc) mrow = Mc - 1;
            vbf8 v8 = *(const vbf8*)(A + (size_t)mrow * 256 + k0 + seg * 8);
            const int byte = row * 128 + ((seg * 16) ^ ((row & 7) << 4));
            *(vbf8*)((char*)a_lds + byte) = v8;
        }
        // stage B tile (f32 -> bf16)
        #pragma unroll
        for (int it = 0; it < 8; ++it) {
            const int u   = tid + it * 256;      // 2048 x 16B units
            const int row = u >> 3;
            const int seg = u & 7;
            const float* s = proj_w + row * 256 + k0 + seg * 8;
            vf4 a = *(const vf4*)s;
            vf4 b = *(const vf4*)(s + 4);
            vbf8 r;
            r[0] = f2bf(a[0]); r[1] = f2bf(a[1]); r[2] = f2bf(a[2]); r[3] = f2bf(a[3]);
            r[4] = f2bf(b[0]); r[5] = f2bf(b[1]); r[6] = f2bf(b[2]); r[7] = f2bf(b[3]);
            const int byte = row * 128 + ((seg * 16) ^ ((row & 7) << 4));
            *(vbf8*)((char*)b_lds + byte) = r;
        }
        __syncthreads();
        #pragma unroll
        for (int ksub = 0; ksub < 2; ++ksub) {
            vbf8 af[4], bfr[4];
            #pragma unroll
            for (int mt = 0; mt < 4; ++mt) {
                const int row  = mt * 16 + c;
                const int byte = row * 128 + (((ksub * 64) + g * 16) ^ ((row & 7) << 4));
                af[mt] = *(const vbf8*)((const char*)a_lds + byte);
            }
            #pragma unroll
            for (int nt = 0; nt < 4; ++nt) {
                const int row  = wave * 64 + nt * 16 + c;
                const int byte = row * 128 + (((ksub * 64) + g * 16) ^ ((row & 7) << 4));
                bfr[nt] = *(const vbf8*)((const char*)b_lds + byte);
            }
            #pragma unroll
            for (int mt = 0; mt < 4; ++mt)
                #pragma unroll
                for (int nt = 0; nt < 4; ++nt)
                    acc[mt][nt] = __builtin_amdgcn_mfma_f32_16x16x32_bf16(af[mt], bfr[nt], acc[mt][nt], 0, 0, 0);
        }
    }
    #pragma unroll
    for (int nt = 0; nt < 4; ++nt) {
        const int n = wave * 64 + nt * 16 + c;
        const float pb = proj_b[n];
        #pragma unroll
        for (int mt = 0; mt < 4; ++mt) {
            #pragma unroll
            for (int r = 0; r < 4; ++r) {
                const int m = m0 + mt * 16 + g * 4 + r;
                if (m < Mc) out[(size_t)m * 256 + n] = acc[mt][nt][r] + pb;
            }
        }
    }
}

extern "C" void kernel_launch(void* const* d_in, const int* in_sizes, int n_in,
                              void* d_out, int out_size, void* d_ws, size_t ws_size,
                              hipStream_t stream)
{
    const float* x      = (const float*)d_in[0];
    const float* qkv_w  = (const float*)d_in[1];
    const float* qkv_b  = (const float*)d_in[2];
    const float* proj_w = (const float*)d_in[3];
    const float* proj_b = (const float*)d_in[4];
    const float* tbl    = (const float*)d_in[5];
    float* out  = (float*)d_out;
    short* attn = (short*)d_ws;

    // attn intermediate needs 4096*53*256*2 B = ~106 MB; chunk windows if d_ws is smaller.
    const size_t bpw = (size_t)NT * CD * 2;
    long cw = (long)(ws_size / bpw);
    if (cw > 4096) cw = 4096;
    cw &= ~7L;                 // multiple of 8 windows (one K1 block)
    if (cw < 8) cw = 8;
    for (int start = 0; start < 4096; start += (int)cw) {
        int count = 4096 - start; if (count > (int)cw) count = (int)cw;
        const int Mc = count * NT;
        k1_fused<<<count / 8, 512, 0, stream>>>(x, qkv_w, qkv_b, tbl, attn, start);
        k2_proj<<<(Mc + 63) / 64, 256, 0, stream>>>(attn, proj_w, proj_b,
                                                    out + (size_t)start * NT * CD, Mc);
    }
    (void)in_sizes; (void)n_in; (void)out_size;
}

// Round 2
// 339.669 us; speedup vs baseline: 1.3465x; 1.3465x over previous
//
#include <hip/hip_runtime.h>

typedef __attribute__((ext_vector_type(8))) short vbf8;   // 8 bf16 = 4 VGPR (MFMA A/B frag)
typedef __attribute__((ext_vector_type(4))) float vf4;    // MFMA C/D frag

#define NT 53
#define CD 256
#define NH 8
#define HIMG 65536          // per-head LDS image: Wq(16K)+Wk(16K)+Wv(16K)+biasT(16K)
#define PROJ_OFF 524288     // proj_w bf16 image offset in ws
#define ATTN_OFF 1048576    // attn intermediate offset in ws

__device__ __forceinline__ short f2bf(float f) {
    union { float f; unsigned u; } v; v.f = f;
    return (short)((v.u + 0x7fffu + ((v.u >> 16) & 1u)) >> 16);  // RNE
}

__device__ __forceinline__ unsigned pk2(float a, float b) {
    unsigned r;
    asm("v_cvt_pk_bf16_f32 %0, %1, %2" : "=v"(r) : "v"(a), "v"(b));
    return r;
}

// Transpose MFMA C-layout (col=c, rows spread over g,reg) into A/B-frag layout
// (lane c keeps its column; 8 contiguous "row" elements per lane, tile selected
// by g'>>1, half by g'&1). Pure-register: 4 cvt_pk + 2 permlane32_swap +
// 4 shfl_xor(16) + 4 selects. A = row-tile 0 acc, B = row-tile 1 acc.
__device__ __forceinline__ vbf8 xpose(vf4 A, vf4 B, int odd) {
    unsigned A0 = pk2(A[0], A[1]), A1 = pk2(A[2], A[3]);
    unsigned B0 = pk2(B[0], B[1]), B1 = pk2(B[2], B[3]);
    asm("v_permlane32_swap_b32 %0, %1" : "+v"(A0), "+v"(B0));  // A=[Alo,Blo] B=[Ahi,Bhi]
    asm("v_permlane32_swap_b32 %0, %1" : "+v"(A1), "+v"(B1));
    unsigned s0 = (unsigned)__shfl_xor((int)B0, 16, 64);
    unsigned s1 = (unsigned)__shfl_xor((int)B1, 16, 64);
    unsigned t0 = (unsigned)__shfl_xor((int)A0, 16, 64);
    unsigned t1 = (unsigned)__shfl_xor((int)A1, 16, 64);
    union { unsigned u[4]; vbf8 v; } r;
    r.u[0] = odd ? s0 : A0;
    r.u[1] = odd ? s1 : A1;
    r.u[2] = odd ? B0 : t0;
    r.u[3] = odd ? B1 : t1;
    return r.v;
}

__device__ __forceinline__ void gl_lds16(const void* g, void* l) {
    __builtin_amdgcn_global_load_lds((const __attribute__((address_space(1))) unsigned*)g,
                                     (__attribute__((address_space(3))) unsigned*)l, 16, 0, 0);
}

// ---------------- Kernel 0: prep (weights->bf16 swizzled LDS images, bias table) --------
__global__ void k0_prep(const float* __restrict__ qkv_w, const float* __restrict__ tbl,
                        const float* __restrict__ proj_w, char* __restrict__ ws)
{
    const int u = (int)blockIdx.x * 256 + (int)threadIdx.x;
    if (u < 24576) {
        // qkv weight images: h(8) x sec(3) x row(32) x seg(32 units of 8 bf16)
        const int h = u / 3072, rem = u - h * 3072;
        const int sec = rem >> 10, rem2 = rem & 1023;
        const int row = rem2 >> 5, seg = rem2 & 31;
        const float* src = qkv_w + ((size_t)(sec * 256 + h * 32 + row)) * 256 + seg * 8;
        const float sc = (sec == 0) ? 0.17677669529663687f : 1.0f;  // fold hd^-0.5 into Wq
        vbf8 r;
        #pragma unroll
        for (int j = 0; j < 8; ++j) r[j] = f2bf(src[j] * sc);
        char* dst = ws + (size_t)h * HIMG + sec * 16384 + row * 512 + ((seg * 16) ^ ((row & 7) << 4));
        *(vbf8*)dst = r;
    } else if (u < 32768) {
        // biasT images: h(8) x q(64) x seg(16 units of 4 f32); biasT[q][key]
        const int t = u - 24576;
        const int h = t >> 10, rem = t & 1023;
        const int q = rem >> 4, seg = rem & 15;
        vf4 r;
        #pragma unroll
        for (int e = 0; e < 4; ++e) {
            const int key = seg * 4 + e;
            float bv;
            if (key >= NT) bv = -1e30f;                          // mask pad keys
            else if (key < 4 || q < 4 || q >= NT) bv = 0.0f;     // carrier rows/cols
            else {
                const int i = q - 4, j = key - 4;
                const int idx = ((i / 7) - (j / 7) + 6) * 13 + ((i % 7) - (j % 7) + 6);
                bv = tbl[idx * NH + h];
            }
            r[e] = bv;
        }
        char* dst = ws + (size_t)h * HIMG + 49152 + q * 256 + ((seg * 16) ^ ((q & 7) << 4));
        *(vf4*)dst = r;
    } else if (u < 40960) {
        // proj_w bf16 image: kc(4) x row(256) x seg(8)
        const int t = u - 32768;
        const int kc = t >> 11, rem = t & 2047;
        const int row = rem >> 3, seg = rem & 7;
        const float* src = proj_w + (size_t)row * 256 + kc * 64 + seg * 8;
        vbf8 r;
        #pragma unroll
        for (int j = 0; j < 8; ++j) r[j] = f2bf(src[j]);
        char* dst = ws + PROJ_OFF + kc * 32768 + row * 128 + ((seg * 16) ^ ((row & 7) << 4));
        *(vbf8*)dst = r;
    }
}

// ---------------- Kernel 1: fused QKV + windowed attention ----------------
// One wave per window, 8 waves/block. All transposes in registers (xpose);
// per-head weights+bias DMA'd (global_load_lds), double-buffered, 1 barrier/head.
// attn output layout: [h][Mtot][32] bf16 (16B/lane stores, full-line writes).
__launch_bounds__(512, 2)
__global__ void k1_fused(const float* __restrict__ x,
                         const float* __restrict__ qkv_b,
                         const char* __restrict__ himg,
                         short* __restrict__ attnH,
                         int win0, int Mtot)
{
    __shared__ char lds[2][HIMG];

    const int tid  = threadIdx.x;
    const int wave = tid >> 6;
    const int lane = tid & 63;
    const int c    = lane & 15;
    const int g    = lane >> 4;
    const int odd  = g & 1;
    const int win  = win0 + (int)blockIdx.x * 8 + wave;

    auto stage = [&](int h, int buf) {
        const char* src = himg + (size_t)h * HIMG;
        #pragma unroll
        for (int i = 0; i < 8; ++i) {
            const int u = tid + i * 512;                       // 16B unit index
            gl_lds16(src + (size_t)u * 16, &lds[buf][(i * 512 + wave * 64) * 16]);
        }
    };

    // prologue: stage head 0
    stage(0, 0);

    // ---- x fragments: xf[t16][ks]: lane holds x[t16*16+c][ks*32+g*8 .. +8] (bf16)
    vbf8 xf[4][8];
    {
        const float* xb = x + (size_t)win * (NT * CD);
        #pragma unroll
        for (int mt = 0; mt < 4; ++mt) {
            const int row = mt * 16 + c;
            const float* src = xb + row * CD + g * 8;
            #pragma unroll
            for (int ks = 0; ks < 8; ++ks) {
                vbf8 r = {0, 0, 0, 0, 0, 0, 0, 0};
                if (row < NT) {
                    vf4 a = *(const vf4*)(src + ks * 32);
                    vf4 b = *(const vf4*)(src + ks * 32 + 4);
                    r[0] = f2bf(a[0]); r[1] = f2bf(a[1]); r[2] = f2bf(a[2]); r[3] = f2bf(a[3]);
                    r[4] = f2bf(b[0]); r[5] = f2bf(b[1]); r[6] = f2bf(b[2]); r[7] = f2bf(b[3]);
                }
                xf[mt][ks] = r;
            }
        }
    }
    __syncthreads();   // drains vmcnt(0): head-0 image staged

    #pragma unroll 1
    for (int h = 0; h < NH; ++h) {
        const int cur = h & 1;
        if (h < 7) stage(h + 1, cur ^ 1);          // prefetch next head under compute
        const char* wb = lds[cur];

        auto rdW = [&](int sec, int rr, int ks) -> vbf8 {
            const int byte = sec * 16384 + rr * 512 + (((ks * 64) + g * 16) ^ ((rr & 7) << 4));
            return *(const vbf8*)(wb + byte);
        };

        // ---------- qT = (scale*Wq) @ x^T ----------
        vf4 qa[2][4];
        #pragma unroll
        for (int mt = 0; mt < 2; ++mt)
            #pragma unroll
            for (int nt = 0; nt < 4; ++nt) { vf4 z = {0.f,0.f,0.f,0.f}; qa[mt][nt] = z; }
        #pragma unroll
        for (int mt = 0; mt < 2; ++mt)
            #pragma unroll
            for (int ks = 0; ks < 8; ++ks) {
                vbf8 wf = rdW(0, mt * 16 + c, ks);
                #pragma unroll
                for (int nt = 0; nt < 4; ++nt)
                    qa[mt][nt] = __builtin_amdgcn_mfma_f32_16x16x32_bf16(wf, xf[nt][ks], qa[mt][nt], 0, 0, 0);
            }
        vbf8 qf[4];
        {
            vf4 b0 = *(const vf4*)(qkv_b + h * 32 + g * 4);
            vf4 b1 = *(const vf4*)(qkv_b + h * 32 + 16 + g * 4);
            const float sc = 0.17677669529663687f;
            #pragma unroll
            for (int nt = 0; nt < 4; ++nt) {
                vf4 A = qa[0][nt], B = qa[1][nt];
                #pragma unroll
                for (int r = 0; r < 4; ++r) { A[r] = fmaf(b0[r], sc, A[r]); B[r] = fmaf(b1[r], sc, B[r]); }
                qf[nt] = xpose(A, B, odd);
            }
        }
        // ---------- kT = Wk @ x^T ----------
        vf4 ka[2][4];
        #pragma unroll
        for (int mt = 0; mt < 2; ++mt)
            #pragma unroll
            for (int nt = 0; nt < 4; ++nt) { vf4 z = {0.f,0.f,0.f,0.f}; ka[mt][nt] = z; }
        #pragma unroll
        for (int mt = 0; mt < 2; ++mt)
            #pragma unroll
            for (int ks = 0; ks < 8; ++ks) {
                vbf8 wf = rdW(1, mt * 16 + c, ks);
                #pragma unroll
                for (int nt = 0; nt < 4; ++nt)
                    ka[mt][nt] = __builtin_amdgcn_mfma_f32_16x16x32_bf16(wf, xf[nt][ks], ka[mt][nt], 0, 0, 0);
            }
        vbf8 kf[4];
        {
            vf4 b0 = *(const vf4*)(qkv_b + 256 + h * 32 + g * 4);
            vf4 b1 = *(const vf4*)(qkv_b + 256 + h * 32 + 16 + g * 4);
            #pragma unroll
            for (int nt = 0; nt < 4; ++nt) {
                vf4 A = ka[0][nt], B = ka[1][nt];
                #pragma unroll
                for (int r = 0; r < 4; ++r) { A[r] += b0[r]; B[r] += b1[r]; }
                kf[nt] = xpose(A, B, odd);
            }
        }
        // ---------- v = x @ Wv^T ----------
        vbf8 vfr[2][2];           // [hd-tile][ks]
        {
            vf4 va[4][2];
            #pragma unroll
            for (int mt = 0; mt < 4; ++mt)
                #pragma unroll
                for (int nv = 0; nv < 2; ++nv) { vf4 z = {0.f,0.f,0.f,0.f}; va[mt][nv] = z; }
            #pragma unroll
            for (int nv = 0; nv < 2; ++nv)
                #pragma unroll
                for (int ks = 0; ks < 8; ++ks) {
                    vbf8 wf = rdW(2, nv * 16 + c, ks);
                    #pragma unroll
                    for (int mt = 0; mt < 4; ++mt)
                        va[mt][nv] = __builtin_amdgcn_mfma_f32_16x16x32_bf16(xf[mt][ks], wf, va[mt][nv], 0, 0, 0);
                }
            #pragma unroll
            for (int nv = 0; nv < 2; ++nv) {
                const float vb = qkv_b[512 + h * 32 + nv * 16 + c];
                #pragma unroll
                for (int mt = 0; mt < 4; ++mt)
                    #pragma unroll
                    for (int r = 0; r < 4; ++r) va[mt][nv][r] += vb;
                #pragma unroll
                for (int ks = 0; ks < 2; ++ks)
                    vfr[nv][ks] = xpose(va[2 * ks][nv], va[2 * ks + 1][nv], odd);
            }
        }
        // ---------- S^T = k @ q^T (scale pre-folded into Wq) ----------
        vf4 st[4][4];
        #pragma unroll
        for (int mk = 0; mk < 4; ++mk)
            #pragma unroll
            for (int nq = 0; nq < 4; ++nq) {
                vf4 z = {0.f,0.f,0.f,0.f};
                st[mk][nq] = __builtin_amdgcn_mfma_f32_16x16x32_bf16(kf[mk], qf[nq], z, 0, 0, 0);
            }
        // ---------- + bias, softmax over keys (per query column) ----------
        const char* bb = wb + 49152;
        float linv[4];
        #pragma unroll
        for (int nq = 0; nq < 4; ++nq) {
            const int row = nq * 16 + c;
            float mx = -3e38f;
            #pragma unroll
            for (int mk = 0; mk < 4; ++mk) {
                vf4 bias = *(const vf4*)(bb + row * 256 + (((mk * 64) + g * 16) ^ ((row & 7) << 4)));
                #pragma unroll
                for (int r = 0; r < 4; ++r) {
                    float s = st[mk][nq][r] + bias[r];
                    st[mk][nq][r] = s;
                    mx = fmaxf(mx, s);
                }
            }
            mx = fmaxf(mx, __shfl_xor(mx, 16, 64));
            mx = fmaxf(mx, __shfl_xor(mx, 32, 64));
            float sum = 0.f;
            #pragma unroll
            for (int mk = 0; mk < 4; ++mk)
                #pragma unroll
                for (int r = 0; r < 4; ++r) {
                    float p = __expf(st[mk][nq][r] - mx);
                    st[mk][nq][r] = p;
                    sum += p;
                }
            sum += __shfl_xor(sum, 16, 64);
            sum += __shfl_xor(sum, 32, 64);
            linv[nq] = 1.f / sum;
        }
        // ---------- pT frags (releases st) ----------
        vbf8 pfr[4][2];
        #pragma unroll
        for (int nq = 0; nq < 4; ++nq)
            #pragma unroll
            for (int ks = 0; ks < 2; ++ks)
                pfr[nq][ks] = xpose(st[2 * ks][nq], st[2 * ks + 1][nq], odd);
        // ---------- out^T = vT @ pT ----------
        vf4 ot[2][4];
        #pragma unroll
        for (int mt = 0; mt < 2; ++mt)
            #pragma unroll
            for (int nq = 0; nq < 4; ++nq) { vf4 z = {0.f,0.f,0.f,0.f}; ot[mt][nq] = z; }
        #pragma unroll
        for (int ks = 0; ks < 2; ++ks)
            #pragma unroll
            for (int mt = 0; mt < 2; ++mt)
                #pragma unroll
                for (int nq = 0; nq < 4; ++nq)
                    ot[mt][nq] = __builtin_amdgcn_mfma_f32_16x16x32_bf16(vfr[mt][ks], pfr[nq][ks], ot[mt][nq], 0, 0, 0);
        // ---------- normalize + write attnH[h][mrow][32] (16B/lane) ----------
        #pragma unroll
        for (int nq = 0; nq < 4; ++nq) {
            vf4 A = ot[0][nq], B = ot[1][nq];
            #pragma unroll
            for (int r = 0; r < 4; ++r) { A[r] *= linv[nq]; B[r] *= linv[nq]; }
            vbf8 o = xpose(A, B, odd);
            const int qq = nq * 16 + c;
            if (qq < NT) {
                const int mrow = (win - win0) * NT + qq;
                *(vbf8*)(attnH + ((size_t)h * Mtot + mrow) * 32 + g * 8) = o;
            }
        }
        __syncthreads();   // drains vmcnt: next head's image staged; buffers safe to swap
    }
}

// ---------------- Kernel 2: output projection GEMM ----------------
// out[m][n] = sum_k attnH[k/32][m][k%32] * projimg + proj_b[n]; BM=64 BN=256 BK=64.
__launch_bounds__(256, 4)
__global__ void k2_proj(const short* __restrict__ attnH,
                        const char* __restrict__ projimg,
                        const float* __restrict__ proj_b,
                        float* __restrict__ out,
                        int Mtot)
{
    __shared__ char a_lds[8192];      // [64 rows][128 B] swizzled
    __shared__ char b_lds[32768];     // [256 rows][128 B] swizzled

    const int tid  = threadIdx.x;
    const int wave = tid >> 6;
    const int lane = tid & 63;
    const int c    = lane & 15;
    const int g    = lane >> 4;
    const int m0   = (int)blockIdx.x * 64;

    vf4 acc[4][4];
    #pragma unroll
    for (int mt = 0; mt < 4; ++mt)
        #pragma unroll
        for (int nt = 0; nt < 4; ++nt) { vf4 z = {0.f,0.f,0.f,0.f}; acc[mt][nt] = z; }

    for (int kc = 0; kc < 4; ++kc) {
        __syncthreads();
        // stage A tile via DMA with swizzle-compensated per-lane source
        #pragma unroll
        for (int rr = 0; rr < 2; ++rr) {
            const int u    = tid + rr * 256;         // 512 units
            const int row  = u >> 3;
            const int sub  = u & 7;
            const int subs = sub ^ (row & 7);
            const int head = kc * 2 + (subs >> 2);
            const int kk   = (subs & 3) * 8;
            int mrow = m0 + row; if (mrow >= Mtot) mrow = Mtot - 1;
            gl_lds16(attnH + ((size_t)head * Mtot + mrow) * 32 + kk,
                     &a_lds[(rr * 256 + wave * 64) * 16]);
        }
        // stage B tile (pre-swizzled image, linear DMA)
        #pragma unroll
        for (int it = 0; it < 8; ++it) {
            const int u = tid + it * 256;            // 2048 units
            gl_lds16(projimg + (size_t)kc * 32768 + (size_t)u * 16,
                     &b_lds[(it * 256 + wave * 64) * 16]);
        }
        __syncthreads();
        #pragma unroll
        for (int ksub = 0; ksub < 2; ++ksub) {
            vbf8 af[4], bfr[4];
            #pragma unroll
            for (int mt = 0; mt < 4; ++mt) {
                const int row = mt * 16 + c;
                af[mt] = *(const vbf8*)(a_lds + row * 128 + (((ksub * 64) + g * 16) ^ ((row & 7) << 4)));
            }
            #pragma unroll
            for (int nt = 0; nt < 4; ++nt) {
                const int row = wave * 64 + nt * 16 + c;
                bfr[nt] = *(const vbf8*)(b_lds + row * 128 + (((ksub * 64) + g * 16) ^ ((row & 7) << 4)));
            }
            #pragma unroll
            for (int mt = 0; mt < 4; ++mt)
                #pragma unroll
                for (int nt = 0; nt < 4; ++nt)
                    acc[mt][nt] = __builtin_amdgcn_mfma_f32_16x16x32_bf16(af[mt], bfr[nt], acc[mt][nt], 0, 0, 0);
        }
    }
    #pragma unroll
    for (int nt = 0; nt < 4; ++nt) {
        const int n = wave * 64 + nt * 16 + c;
        const float pb = proj_b[n];
        #pragma unroll
        for (int mt = 0; mt < 4; ++mt)
            #pragma unroll
            for (int r = 0; r < 4; ++r) {
                const int m = m0 + mt * 16 + g * 4 + r;
                if (m < Mtot) out[(size_t)m * 256 + n] = acc[mt][nt][r] + pb;
            }
    }
}

extern "C" void kernel_launch(void* const* d_in, const int* in_sizes, int n_in,
                              void* d_out, int out_size, void* d_ws, size_t ws_size,
                              hipStream_t stream)
{
    const float* x      = (const float*)d_in[0];
    const float* qkv_w  = (const float*)d_in[1];
    const float* qkv_b  = (const float*)d_in[2];
    const float* proj_w = (const float*)d_in[3];
    const float* proj_b = (const float*)d_in[4];
    const float* tbl    = (const float*)d_in[5];
    float* out = (float*)d_out;
    char* ws   = (char*)d_ws;

    k0_prep<<<160, 256, 0, stream>>>(qkv_w, tbl, proj_w, ws);

    short* attn = (short*)(ws + ATTN_OFF);
    const size_t bpw = (size_t)NT * 32 * 2 * NH;   // bytes per window in attn area
    long cw = (ws_size > ATTN_OFF) ? (long)((ws_size - ATTN_OFF) / bpw) : 8;
    if (cw > 4096) cw = 4096;
    cw &= ~7L;
    if (cw < 8) cw = 8;
    for (int start = 0; start < 4096; start += (int)cw) {
        int count = 4096 - start; if (count > (int)cw) count = (int)cw;
        const int Mc = count * NT;
        k1_fused<<<count / 8, 512, 0, stream>>>(x, qkv_b, ws, attn, start, Mc);
        k2_proj<<<(Mc + 63) / 64, 256, 0, stream>>>(attn, ws + PROJ_OFF, proj_b,
                                                    out + (size_t)start * NT * CD, Mc);
    }
    (void)in_sizes; (void)n_in; (void)out_size;
}

// Round 5
// 336.877 us; speedup vs baseline: 1.3577x; 1.0083x over previous
//
#include <hip/hip_runtime.h>

typedef __attribute__((ext_vector_type(8))) short vbf8;   // 8 bf16 = 4 VGPR (K=32 MFMA A/B frag)
typedef __attribute__((ext_vector_type(4))) float vf4;    // MFMA C/D frag

#define NT 53
#define CD 256
#define NH 8
#define HIMG 65536          // per-head LDS image: Wq(16K)+Wk(16K)+Wv(16K)+biasT f32(16K)
#define PROJ_OFF 524288     // proj_w bf16 image offset in ws
#define QBS_OFF  655360     // scaled qkv_b table (768 f32)
#define ATTN_OFF 1048576    // attn intermediate offset in ws

#define LOG2E 1.4426950408889634f
#define SCALE 0.17677669529663687f   // 32^-0.5

__device__ __forceinline__ unsigned pk2(float a, float b) {
    unsigned r;
    asm("v_cvt_pk_bf16_f32 %0, %1, %2" : "=v"(r) : "v"(a), "v"(b));
    return r;
}

// Transpose MFMA C-layout (col=c, rows over g,reg) into K=32-frag layout
// (lane keeps col; 8 contiguous row-elems per lane). Proven in rounds 1-2.
__device__ __forceinline__ vbf8 xpose(vf4 A, vf4 B, int odd) {
    unsigned A0 = pk2(A[0], A[1]), A1 = pk2(A[2], A[3]);
    unsigned B0 = pk2(B[0], B[1]), B1 = pk2(B[2], B[3]);
    asm("v_permlane32_swap_b32 %0, %1" : "+v"(A0), "+v"(B0));
    asm("v_permlane32_swap_b32 %0, %1" : "+v"(A1), "+v"(B1));
    unsigned s0 = (unsigned)__shfl_xor((int)B0, 16, 64);
    unsigned s1 = (unsigned)__shfl_xor((int)B1, 16, 64);
    unsigned t0 = (unsigned)__shfl_xor((int)A0, 16, 64);
    unsigned t1 = (unsigned)__shfl_xor((int)A1, 16, 64);
    union { unsigned u[4]; vbf8 v; } r;
    r.u[0] = odd ? s0 : A0;
    r.u[1] = odd ? s1 : A1;
    r.u[2] = odd ? B0 : t0;
    r.u[3] = odd ? B1 : t1;
    return r.v;
}

__device__ __forceinline__ void gl_lds16(const void* g, void* l) {
    __builtin_amdgcn_global_load_lds((const __attribute__((address_space(1))) unsigned*)g,
                                     (__attribute__((address_space(3))) unsigned*)l, 16, 0, 0);
}

// ---------------- Kernel 0: prep ----------------
// ws: [0,512K) per-head {Wq*scale*log2e, Wk, Wv (bf16 swizzled), biasT*log2e (f32 swizzled)}
//     [512K,640K) proj_w bf16 swizzled; [QBS_OFF) scaled qkv_b (768 f32).
__global__ void k0_prep(const float* __restrict__ qkv_w, const float* __restrict__ tbl,
                        const float* __restrict__ proj_w, const float* __restrict__ qkv_b,
                        char* __restrict__ ws)
{
    const int u = (int)blockIdx.x * 256 + (int)threadIdx.x;
    if (u < 24576) {
        // qkv weight images: h(8) x sec(3) x row(32) x seg(32 units of 8 bf16)
        const int h = u / 3072, rem = u - h * 3072;
        const int sec = rem >> 10, rem2 = rem & 1023;
        const int row = rem2 >> 5, seg = rem2 & 31;
        const float* src = qkv_w + ((size_t)(sec * 256 + h * 32 + row)) * 256 + seg * 8;
        const float sc = (sec == 0) ? SCALE * LOG2E : 1.0f;
        vf4 a = *(const vf4*)src;
        vf4 b = *(const vf4*)(src + 4);
        union { unsigned w[4]; vbf8 v; } r;
        r.w[0] = pk2(a[0] * sc, a[1] * sc); r.w[1] = pk2(a[2] * sc, a[3] * sc);
        r.w[2] = pk2(b[0] * sc, b[1] * sc); r.w[3] = pk2(b[2] * sc, b[3] * sc);
        char* dst = ws + (size_t)h * HIMG + sec * 16384 + row * 512 + ((seg * 16) ^ ((row & 7) << 4));
        *(vbf8*)dst = r.v;
    } else if (u < 32768) {
        // biasT images (f32, *log2e): h(8) x q(64) x seg(16 units of 4 f32); biasT[q][key]
        const int t = u - 24576;
        const int h = t >> 10, rem = t & 1023;
        const int q = rem >> 4, seg = rem & 15;
        vf4 r;
        #pragma unroll
        for (int e = 0; e < 4; ++e) {
            const int key = seg * 4 + e;
            float bv;
            if (key >= NT) bv = -1e30f;                          // mask pad keys
            else if (key < 4 || q < 4 || q >= NT) bv = 0.0f;     // carrier rows/cols
            else {
                const int i = q - 4, j = key - 4;
                const int idx = ((i / 7) - (j / 7) + 6) * 13 + ((i % 7) - (j % 7) + 6);
                bv = tbl[idx * NH + h] * LOG2E;
            }
            r[e] = bv;
        }
        char* dst = ws + (size_t)h * HIMG + 49152 + q * 256 + ((seg * 16) ^ ((q & 7) << 4));
        *(vf4*)dst = r;
    } else if (u < 40960) {
        // proj_w bf16 image: kc(4) x row(256) x seg(8)
        const int t = u - 32768;
        const int kc = t >> 11, rem = t & 2047;
        const int row = rem >> 3, seg = rem & 7;
        const float* src = proj_w + (size_t)row * 256 + kc * 64 + seg * 8;
        vf4 a = *(const vf4*)src;
        vf4 b = *(const vf4*)(src + 4);
        union { unsigned w[4]; vbf8 v; } r;
        r.w[0] = pk2(a[0], a[1]); r.w[1] = pk2(a[2], a[3]);
        r.w[2] = pk2(b[0], b[1]); r.w[3] = pk2(b[2], b[3]);
        char* dst = ws + PROJ_OFF + kc * 32768 + row * 128 + ((seg * 16) ^ ((row & 7) << 4));
        *(vbf8*)dst = r.v;
    } else if (u < 41152) {
        // scaled qkv_b: [0,256) *scale*log2e (Q), rest raw
        const int i = (u - 40960) * 4;
        float* dst = (float*)(ws + QBS_OFF);
        #pragma unroll
        for (int e = 0; e < 4; ++e) {
            const int j = i + e;
            dst[j] = qkv_b[j] * (j < 256 ? SCALE * LOG2E : 1.0f);
        }
    }
}

// ---------------- Kernel 1: fused QKV + windowed attention ----------------
// Proven round-2 config: 512 threads, 8 waves, one window/wave, 128 KB
// double-buffered head image, 1 barrier/head. New (verified analytically):
// biases as MFMA C-inits, exp2-domain softmax, setprio around MFMA clusters.
__launch_bounds__(512, 2)
__global__ void k1_fused(const float* __restrict__ x,
                         const float* __restrict__ qbs,
                         const char* __restrict__ himg,
                         short* __restrict__ attnH,
                         int win0, int Mtot)
{
    __shared__ char lds[2][HIMG];

    const int tid  = threadIdx.x;
    const int wave = tid >> 6;
    const int lane = tid & 63;
    const int c    = lane & 15;
    const int g    = lane >> 4;
    const int odd  = g & 1;
    const int win  = win0 + (int)blockIdx.x * 8 + wave;

    auto stage = [&](int h, int buf) {
        const char* src = himg + (size_t)h * HIMG;
        #pragma unroll
        for (int i = 0; i < 8; ++i) {
            const int u = tid + i * 512;                       // 16B unit index
            gl_lds16(src + (size_t)u * 16, &lds[buf][(i * 512 + wave * 64) * 16]);
        }
    };

    stage(0, 0);   // prologue: head-0 image

    // ---- x fragments: xf[t16][ks]: lane holds x[t16*16+c][ks*32+g*8 .. +8] (bf16)
    vbf8 xf[4][8];
    {
        const float* xb = x + (size_t)win * (NT * CD);
        #pragma unroll
        for (int mt = 0; mt < 4; ++mt) {
            const int row = mt * 16 + c;
            const float* src = xb + row * CD + g * 8;
            #pragma unroll
            for (int ks = 0; ks < 8; ++ks) {
                vbf8 z = {0, 0, 0, 0, 0, 0, 0, 0};
                if (row < NT) {
                    vf4 a = *(const vf4*)(src + ks * 32);
                    vf4 b = *(const vf4*)(src + ks * 32 + 4);
                    union { unsigned w[4]; vbf8 v; } r;
                    r.w[0] = pk2(a[0], a[1]); r.w[1] = pk2(a[2], a[3]);
                    r.w[2] = pk2(b[0], b[1]); r.w[3] = pk2(b[2], b[3]);
                    z = r.v;
                }
                xf[mt][ks] = z;
            }
        }
    }
    __syncthreads();   // head-0 image staged (barrier drains vmcnt)

    #pragma unroll 1
    for (int h = 0; h < NH; ++h) {
        const int cur = h & 1;
        if (h < 7) stage(h + 1, cur ^ 1);          // prefetch next head under compute
        const char* wb = lds[cur];

        auto rdW = [&](int sec, int rr, int ks) -> vbf8 {
            const int byte = sec * 16384 + rr * 512 + (((ks * 64) + g * 16) ^ ((rr & 7) << 4));
            return *(const vbf8*)(wb + byte);
        };

        // ---------- qT = (scale*log2e*Wq) @ x^T, bias as C-init ----------
        vf4 qa[2][4];
        #pragma unroll
        for (int mt = 0; mt < 2; ++mt) {
            vf4 bi = *(const vf4*)(qbs + h * 32 + mt * 16 + g * 4);
            #pragma unroll
            for (int nt = 0; nt < 4; ++nt) qa[mt][nt] = bi;
        }
        __builtin_amdgcn_s_setprio(1);
        #pragma unroll
        for (int mt = 0; mt < 2; ++mt)
            #pragma unroll
            for (int ks = 0; ks < 8; ++ks) {
                vbf8 wf = rdW(0, mt * 16 + c, ks);
                #pragma unroll
                for (int nt = 0; nt < 4; ++nt)
                    qa[mt][nt] = __builtin_amdgcn_mfma_f32_16x16x32_bf16(wf, xf[nt][ks], qa[mt][nt], 0, 0, 0);
            }
        __builtin_amdgcn_s_setprio(0);
        vbf8 qf[4];
        #pragma unroll
        for (int nt = 0; nt < 4; ++nt) qf[nt] = xpose(qa[0][nt], qa[1][nt], odd);

        // ---------- kT = Wk @ x^T, bias as C-init ----------
        vf4 ka[2][4];
        #pragma unroll
        for (int mt = 0; mt < 2; ++mt) {
            vf4 bi = *(const vf4*)(qbs + 256 + h * 32 + mt * 16 + g * 4);
            #pragma unroll
            for (int nt = 0; nt < 4; ++nt) ka[mt][nt] = bi;
        }
        __builtin_amdgcn_s_setprio(1);
        #pragma unroll
        for (int mt = 0; mt < 2; ++mt)
            #pragma unroll
            for (int ks = 0; ks < 8; ++ks) {
                vbf8 wf = rdW(1, mt * 16 + c, ks);
                #pragma unroll
                for (int nt = 0; nt < 4; ++nt)
                    ka[mt][nt] = __builtin_amdgcn_mfma_f32_16x16x32_bf16(wf, xf[nt][ks], ka[mt][nt], 0, 0, 0);
            }
        __builtin_amdgcn_s_setprio(0);
        vbf8 kf[4];
        #pragma unroll
        for (int nt = 0; nt < 4; ++nt) kf[nt] = xpose(ka[0][nt], ka[1][nt], odd);

        // ---------- v = x @ Wv^T, bias as C-init (splat over rows) ----------
        vbf8 vfr[2][2];           // [hd-tile][ks]
        {
            vf4 va[4][2];
            #pragma unroll
            for (int nv = 0; nv < 2; ++nv) {
                const float vb = qbs[512 + h * 32 + nv * 16 + c];
                vf4 bi = {vb, vb, vb, vb};
                #pragma unroll
                for (int mt = 0; mt < 4; ++mt) va[mt][nv] = bi;
            }
            __builtin_amdgcn_s_setprio(1);
            #pragma unroll
            for (int nv = 0; nv < 2; ++nv)
                #pragma unroll
                for (int ks = 0; ks < 8; ++ks) {
                    vbf8 wf = rdW(2, nv * 16 + c, ks);
                    #pragma unroll
                    for (int mt = 0; mt < 4; ++mt)
                        va[mt][nv] = __builtin_amdgcn_mfma_f32_16x16x32_bf16(xf[mt][ks], wf, va[mt][nv], 0, 0, 0);
                }
            __builtin_amdgcn_s_setprio(0);
            #pragma unroll
            for (int nv = 0; nv < 2; ++nv)
                #pragma unroll
                for (int ks = 0; ks < 2; ++ks)
                    vfr[nv][ks] = xpose(va[2 * ks][nv], va[2 * ks + 1][nv], odd);
        }

        // ---------- S^T = k @ q^T, bias as C-init ----------
        const char* bb = wb + 49152;
        vf4 st[4][4];     // [key-tile][q-tile]: col=q(c), row=key(4g+r)
        #pragma unroll
        for (int nq = 0; nq < 4; ++nq) {
            const int row = nq * 16 + c;
            #pragma unroll
            for (int mk = 0; mk < 4; ++mk)
                st[mk][nq] = *(const vf4*)(bb + row * 256 + (((mk * 64) + g * 16) ^ ((row & 7) << 4)));
        }
        __builtin_amdgcn_s_setprio(1);
        #pragma unroll
        for (int mk = 0; mk < 4; ++mk)
            #pragma unroll
            for (int nq = 0; nq < 4; ++nq)
                st[mk][nq] = __builtin_amdgcn_mfma_f32_16x16x32_bf16(kf[mk], qf[nq], st[mk][nq], 0, 0, 0);
        __builtin_amdgcn_s_setprio(0);

        // ---------- softmax over keys (exp2 domain) ----------
        float linv[4];
        #pragma unroll
        for (int nq = 0; nq < 4; ++nq) {
            float mx = -3e38f;
            #pragma unroll
            for (int mk = 0; mk < 4; ++mk)
                #pragma unroll
                for (int r = 0; r < 4; ++r) mx = fmaxf(mx, st[mk][nq][r]);
            mx = fmaxf(mx, __shfl_xor(mx, 16, 64));
            mx = fmaxf(mx, __shfl_xor(mx, 32, 64));
            float sum = 0.f;
            #pragma unroll
            for (int mk = 0; mk < 4; ++mk)
                #pragma unroll
                for (int r = 0; r < 4; ++r) {
                    float p = exp2f(st[mk][nq][r] - mx);
                    st[mk][nq][r] = p;
                    sum += p;
                }
            sum += __shfl_xor(sum, 16, 64);
            sum += __shfl_xor(sum, 32, 64);
            linv[nq] = 1.f / sum;
        }

        // ---------- pT frags ----------
        vbf8 pfr[4][2];
        #pragma unroll
        for (int nq = 0; nq < 4; ++nq)
            #pragma unroll
            for (int ks = 0; ks < 2; ++ks)
                pfr[nq][ks] = xpose(st[2 * ks][nq], st[2 * ks + 1][nq], odd);

        // ---------- out^T = vT @ pT ----------
        vf4 ot[2][4];
        #pragma unroll
        for (int mt = 0; mt < 2; ++mt)
            #pragma unroll
            for (int nq = 0; nq < 4; ++nq) { vf4 z = {0.f,0.f,0.f,0.f}; ot[mt][nq] = z; }
        __builtin_amdgcn_s_setprio(1);
        #pragma unroll
        for (int ks = 0; ks < 2; ++ks)
            #pragma unroll
            for (int mt = 0; mt < 2; ++mt)
                #pragma unroll
                for (int nq = 0; nq < 4; ++nq)
                    ot[mt][nq] = __builtin_amdgcn_mfma_f32_16x16x32_bf16(vfr[mt][ks], pfr[nq][ks], ot[mt][nq], 0, 0, 0);
        __builtin_amdgcn_s_setprio(0);

        // ---------- normalize + write attnH[h][mrow][32] (16B/lane) ----------
        #pragma unroll
        for (int nq = 0; nq < 4; ++nq) {
            vf4 A = ot[0][nq], B = ot[1][nq];
            #pragma unroll
            for (int r = 0; r < 4; ++r) { A[r] *= linv[nq]; B[r] *= linv[nq]; }
            vbf8 o = xpose(A, B, odd);
            const int qq = nq * 16 + c;
            if (qq < NT) {
                const int mrow = (win - win0) * NT + qq;
                *(vbf8*)(attnH + ((size_t)h * Mtot + mrow) * 32 + g * 8) = o;
            }
        }
        __syncthreads();   // next head's image staged; buffer swap safe
    }
}

// ---------------- Kernel 2: output projection GEMM (unchanged, proven) ----------------
__launch_bounds__(256, 4)
__global__ void k2_proj(const short* __restrict__ attnH,
                        const char* __restrict__ projimg,
                        const float* __restrict__ proj_b,
                        float* __restrict__ out,
                        int Mtot)
{
    __shared__ char a_lds[8192];      // [64 rows][128 B] swizzled
    __shared__ char b_lds[32768];     // [256 rows][128 B] swizzled

    const int tid  = threadIdx.x;
    const int wave = tid >> 6;
    const int lane = tid & 63;
    const int c    = lane & 15;
    const int g    = lane >> 4;
    const int m0   = (int)blockIdx.x * 64;

    vf4 acc[4][4];
    #pragma unroll
    for (int mt = 0; mt < 4; ++mt)
        #pragma unroll
        for (int nt = 0; nt < 4; ++nt) { vf4 z = {0.f,0.f,0.f,0.f}; acc[mt][nt] = z; }

    for (int kc = 0; kc < 4; ++kc) {
        __syncthreads();
        // stage A tile via DMA with swizzle-compensated per-lane source
        #pragma unroll
        for (int rr = 0; rr < 2; ++rr) {
            const int u    = tid + rr * 256;         // 512 units
            const int row  = u >> 3;
            const int sub  = u & 7;
            const int subs = sub ^ (row & 7);
            const int head = kc * 2 + (subs >> 2);
            const int kk   = (subs & 3) * 8;
            int mrow = m0 + row; if (mrow >= Mtot) mrow = Mtot - 1;
            gl_lds16(attnH + ((size_t)head * Mtot + mrow) * 32 + kk,
                     &a_lds[(rr * 256 + wave * 64) * 16]);
        }
        // stage B tile (pre-swizzled image, linear DMA)
        #pragma unroll
        for (int it = 0; it < 8; ++it) {
            const int u = tid + it * 256;            // 2048 units
            gl_lds16(projimg + (size_t)kc * 32768 + (size_t)u * 16,
                     &b_lds[(it * 256 + wave * 64) * 16]);
        }
        __syncthreads();
        #pragma unroll
        for (int ksub = 0; ksub < 2; ++ksub) {
            vbf8 af[4], bfr[4];
            #pragma unroll
            for (int mt = 0; mt < 4; ++mt) {
                const int row = mt * 16 + c;
                af[mt] = *(const vbf8*)(a_lds + row * 128 + (((ksub * 64) + g * 16) ^ ((row & 7) << 4)));
            }
            #pragma unroll
            for (int nt = 0; nt < 4; ++nt) {
                const int row = wave * 64 + nt * 16 + c;
                bfr[nt] = *(const vbf8*)(b_lds + row * 128 + (((ksub * 64) + g * 16) ^ ((row & 7) << 4)));
            }
            #pragma unroll
            for (int mt = 0; mt < 4; ++mt)
                #pragma unroll
                for (int nt = 0; nt < 4; ++nt)
                    acc[mt][nt] = __builtin_amdgcn_mfma_f32_16x16x32_bf16(af[mt], bfr[nt], acc[mt][nt], 0, 0, 0);
        }
    }
    #pragma unroll
    for (int nt = 0; nt < 4; ++nt) {
        const int n = wave * 64 + nt * 16 + c;
        const float pb = proj_b[n];
        #pragma unroll
        for (int mt = 0; mt < 4; ++mt)
            #pragma unroll
            for (int r = 0; r < 4; ++r) {
                const int m = m0 + mt * 16 + g * 4 + r;
                if (m < Mtot) out[(size_t)m * 256 + n] = acc[mt][nt][r] + pb;
            }
    }
}

extern "C" void kernel_launch(void* const* d_in, const int* in_sizes, int n_in,
                              void* d_out, int out_size, void* d_ws, size_t ws_size,
                              hipStream_t stream)
{
    const float* x      = (const float*)d_in[0];
    const float* qkv_w  = (const float*)d_in[1];
    const float* qkv_b  = (const float*)d_in[2];
    const float* proj_w = (const float*)d_in[3];
    const float* proj_b = (const float*)d_in[4];
    const float* tbl    = (const float*)d_in[5];
    float* out = (float*)d_out;
    char* ws   = (char*)d_ws;

    k0_prep<<<161, 256, 0, stream>>>(qkv_w, tbl, proj_w, qkv_b, ws);

    short* attn = (short*)(ws + ATTN_OFF);
    const float* qbs = (const float*)(ws + QBS_OFF);
    const size_t bpw = (size_t)NT * 32 * 2 * NH;   // bytes per window in attn area
    long cw = (ws_size > ATTN_OFF) ? (long)((ws_size - ATTN_OFF) / bpw) : 8;
    if (cw > 4096) cw = 4096;
    cw &= ~7L;
    if (cw < 8) cw = 8;
    for (int start = 0; start < 4096; start += (int)cw) {
        int count = 4096 - start; if (count > (int)cw) count = (int)cw;
        const int Mc = count * NT;
        k1_fused<<<count / 8, 512, 0, stream>>>(x, qbs, ws, attn, start, Mc);
        k2_proj<<<(Mc + 63) / 64, 256, 0, stream>>>(attn, ws + PROJ_OFF, proj_b,
                                                    out + (size_t)start * NT * CD, Mc);
    }
    (void)in_sizes; (void)n_in; (void)out_size;
}